// Round 1
// baseline (234.569 us; speedup 1.0000x reference)
//
#include <hip/hip_runtime.h>
#include <stdint.h>

// WildCatPooling: per row of HW=4096 f32, mean of top-410 + 0.6 * mean of bottom-410.
// One block per row; exact radix-select (8-bit MSB-first, 4 levels) on
// monotonic u32 keys kept in registers; histogram in LDS; wave-0 shfl suffix scan.

#define HW   4096
#define NT   256
#define VPT  (HW / NT)   // 16 values per thread
#define KSEL 410         // round(4096 * 0.1)
#define ALPHA_C 0.6f

__device__ __forceinline__ uint32_t f2u(float f) {
  uint32_t b = __float_as_uint(f);
  // order-preserving map: ascending u <=> ascending float
  return b ^ (uint32_t)(((int32_t)b >> 31) | 0x80000000);
}
__device__ __forceinline__ float u2f(uint32_t u) {
  uint32_t b = (u & 0x80000000u) ? (u ^ 0x80000000u) : ~u;
  return __uint_as_float(b);
}

__global__ __launch_bounds__(NT)
void wildcat_pool(const float* __restrict__ x, float* __restrict__ out) {
  const int row = blockIdx.x;
  const float* rp = x + (size_t)row * HW;
  const int tid = threadIdx.x;

  // ---- load 16 floats/thread, coalesced float4, keep monotonic keys in regs ----
  uint32_t key[VPT];
#pragma unroll
  for (int i = 0; i < VPT / 4; ++i) {
    float4 v = reinterpret_cast<const float4*>(rp)[i * NT + tid];
    key[i * 4 + 0] = f2u(v.x);
    key[i * 4 + 1] = f2u(v.y);
    key[i * 4 + 2] = f2u(v.z);
    key[i * 4 + 3] = f2u(v.w);
  }

  __shared__ uint32_t hist[256];
  __shared__ uint32_t s_bucket, s_above;
  __shared__ float    s_red[NT / 64];

  float resTop = 0.f, resBot = 0.f;

#pragma unroll
  for (int pass = 0; pass < 2; ++pass) {
    // pass 0: top-K on u; pass 1: top-K on ~u (== bottom-K on u)
    uint32_t prefix = 0u, pmask = 0u;
    uint32_t krem = KSEL;

    for (int level = 0; level < 4; ++level) {
      const int shift = 24 - 8 * level;
      hist[tid] = 0u;
      __syncthreads();
#pragma unroll
      for (int i = 0; i < VPT; ++i) {
        uint32_t u = pass ? ~key[i] : key[i];
        if ((u & pmask) == prefix)
          atomicAdd(&hist[(u >> shift) & 255u], 1u);
      }
      __syncthreads();

      // wave 0: suffix-scan 256 buckets (4 per lane) to find crossing bucket
      if (tid < 64) {
        uint32_t h0 = hist[4 * tid + 0], h1 = hist[4 * tid + 1];
        uint32_t h2 = hist[4 * tid + 2], h3 = hist[4 * tid + 3];
        uint32_t lsum = h0 + h1 + h2 + h3;
        uint32_t s = lsum;
#pragma unroll
        for (int off = 1; off < 64; off <<= 1) {
          uint32_t o = __shfl_down(s, off, 64);
          if (tid + off < 64) s += o;
        }
        // count of elements in buckets strictly above each bucket of this group
        uint32_t a3 = s - lsum;
        uint32_t a2 = a3 + h3;
        uint32_t a1 = a2 + h2;
        uint32_t a0 = a1 + h1;
        // exactly one bucket satisfies (above < krem <= above + h)
        if (a0 < krem && krem <= a0 + h0) { s_bucket = 4u * tid + 0u; s_above = a0; }
        if (a1 < krem && krem <= a1 + h1) { s_bucket = 4u * tid + 1u; s_above = a1; }
        if (a2 < krem && krem <= a2 + h2) { s_bucket = 4u * tid + 2u; s_above = a2; }
        if (a3 < krem && krem <= a3 + h3) { s_bucket = 4u * tid + 3u; s_above = a3; }
      }
      __syncthreads();
      prefix |= (s_bucket << shift);
      pmask  |= (0xFFu << shift);
      krem   -= s_above;
    }
    // prefix = k-th extreme key (transformed space); krem = copies of it to take

    // ---- sum elements strictly beyond threshold, add krem * threshold ----
    float s = 0.f;
#pragma unroll
    for (int i = 0; i < VPT; ++i) {
      uint32_t u = pass ? ~key[i] : key[i];
      if (u > prefix) s += u2f(key[i]);
    }
#pragma unroll
    for (int off = 32; off >= 1; off >>= 1) s += __shfl_down(s, off, 64);
    if ((tid & 63) == 0) s_red[tid >> 6] = s;
    __syncthreads();
    if (tid == 0) {
      float tot = s_red[0] + s_red[1] + s_red[2] + s_red[3];
      tot += (float)krem * u2f(pass ? ~prefix : prefix);
      if (pass == 0) resTop = tot; else resBot = tot;
    }
    __syncthreads();  // protect s_red/hist before next pass reuses them
  }

  if (tid == 0) out[row] = (resTop + ALPHA_C * resBot) * (1.0f / (float)KSEL);
}

extern "C" void kernel_launch(void* const* d_in, const int* in_sizes, int n_in,
                              void* d_out, int out_size, void* d_ws, size_t ws_size,
                              hipStream_t stream) {
  const float* x = (const float*)d_in[0];
  float* out = (float*)d_out;
  const int rows = out_size;  // 32 * 512 = 16384
  wildcat_pool<<<rows, NT, 0, stream>>>(x, out);
}

// Round 2
// 130.720 us; speedup vs baseline: 1.7944x; 1.7944x over previous
//
#include <hip/hip_runtime.h>
#include <stdint.h>

// WildCatPooling: per row of HW=4096 f32, mean(top-410) + 0.6 * mean(bottom-410).
// One block/row. Exact radix select on monotonic u32 keys, 3 levels (12+10+10 bits).
// Level 0: one shared 4096-bucket histogram serves BOTH top and bottom crossings
// (block prefix scan). Levels 1-2: top on wave 0, bottom on wave 1, concurrently.

#define HW   4096
#define NT   256
#define VPT  16          // values per thread
#define KSEL 410         // round(4096 * 0.1)
#define ALPHA_C 0.6f

__device__ __forceinline__ uint32_t f2u(float f) {
  uint32_t b = __float_as_uint(f);
  return b ^ (uint32_t)(((int32_t)b >> 31) | 0x80000000);  // ascending u <=> ascending float
}
__device__ __forceinline__ float u2f(uint32_t u) {
  uint32_t b = (u & 0x80000000u) ? (u ^ 0x80000000u) : ~u;
  return __uint_as_float(b);
}

// Wave-local select over a 1024-bucket histogram (16 buckets/lane, uint4 reads).
// Zeroes the histogram behind itself so the next level can reuse it barrier-free.
// isTop: crossing counted from the high end; else from the low end.
__device__ __forceinline__ void wave_select(uint32_t* hist, int lane, bool isTop,
                                            uint32_t total, uint32_t kneed,
                                            uint32_t* s_bkt, uint32_t* s_k, uint32_t* s_c) {
  uint4* h4 = reinterpret_cast<uint4*>(hist);
  uint32_t pref[16];
  uint32_t lsum = 0;
#pragma unroll
  for (int j = 0; j < 4; ++j) {
    uint4 a = h4[lane * 4 + j];
    pref[4 * j + 0] = lsum + a.x;
    pref[4 * j + 1] = pref[4 * j + 0] + a.y;
    pref[4 * j + 2] = pref[4 * j + 1] + a.z;
    pref[4 * j + 3] = pref[4 * j + 2] + a.w;
    lsum = pref[4 * j + 3];
    h4[lane * 4 + j] = make_uint4(0, 0, 0, 0);  // zero for next level (own lanes only)
  }
  uint32_t sc = lsum;
#pragma unroll
  for (int off = 1; off < 64; off <<= 1) {
    uint32_t o = __shfl_up(sc, off, 64);
    if (lane >= off) sc += o;
  }
  uint32_t base = sc - lsum;  // exclusive prefix of this lane's chunk
  uint32_t X = isTop ? (total - kneed) : (kneed - 1u);
#pragma unroll
  for (int j = 0; j < 16; ++j) {
    uint32_t pin = base + pref[j];
    uint32_t pex = base + (j ? pref[j - 1] : 0u);
    if (pex <= X && X < pin) {       // unique crossing bucket
      *s_bkt = (uint32_t)(lane * 16 + j);
      *s_c   = pin - pex;
      *s_k   = isTop ? (kneed - (total - pin)) : (kneed - pex);
    }
  }
}

__global__ __launch_bounds__(NT)
void wildcat_pool(const float* __restrict__ x, float* __restrict__ out) {
  const int tid  = threadIdx.x;
  const int lane = tid & 63;
  const int wid  = tid >> 6;
  const float* rp = x + (size_t)blockIdx.x * HW;

  __shared__ uint32_t h0[4096];     // level-0, 12-bit buckets
  __shared__ uint32_t ht[1024];     // top refinement, 10-bit
  __shared__ uint32_t hb[1024];     // bottom refinement, 10-bit
  __shared__ uint32_t s_wtot[4];
  __shared__ uint32_t s_bT, s_kT, s_cT, s_bT1, s_bT2;
  __shared__ uint32_t s_bB, s_kB, s_cB, s_bB1, s_bB2;
  __shared__ float    s_red[4][2];

  // ---- zero histograms (uint4 stores) ----
  uint4 z4 = make_uint4(0, 0, 0, 0);
#pragma unroll
  for (int i = 0; i < 4; ++i) reinterpret_cast<uint4*>(h0)[tid + i * NT] = z4;
  reinterpret_cast<uint4*>(ht)[tid] = z4;
  reinterpret_cast<uint4*>(hb)[tid] = z4;

  // ---- load 16 floats/thread (coalesced float4), keys stay in registers ----
  uint32_t key[VPT];
#pragma unroll
  for (int i = 0; i < 4; ++i) {
    float4 v = reinterpret_cast<const float4*>(rp)[i * NT + tid];
    key[4 * i + 0] = f2u(v.x);
    key[4 * i + 1] = f2u(v.y);
    key[4 * i + 2] = f2u(v.z);
    key[4 * i + 3] = f2u(v.w);
  }
  __syncthreads();

  // ---- level 0: build 12-bit histogram (low contention: normal data spreads) ----
#pragma unroll
  for (int i = 0; i < VPT; ++i) atomicAdd(&h0[key[i] >> 20], 1u);
  __syncthreads();

  // ---- level 0: block prefix scan of 4096 buckets; detect BOTH crossings ----
  uint32_t pref[16];
  uint32_t lsum = 0;
#pragma unroll
  for (int j = 0; j < 4; ++j) {
    uint4 a = reinterpret_cast<uint4*>(h0)[tid * 4 + j];
    pref[4 * j + 0] = lsum + a.x;
    pref[4 * j + 1] = pref[4 * j + 0] + a.y;
    pref[4 * j + 2] = pref[4 * j + 1] + a.z;
    pref[4 * j + 3] = pref[4 * j + 2] + a.w;
    lsum = pref[4 * j + 3];
  }
  uint32_t sc = lsum;
#pragma unroll
  for (int off = 1; off < 64; off <<= 1) {
    uint32_t o = __shfl_up(sc, off, 64);
    if (lane >= off) sc += o;
  }
  if (lane == 63) s_wtot[wid] = sc;
  __syncthreads();
  uint32_t base = sc - lsum;
#pragma unroll
  for (int w = 0; w < 4; ++w) if (w < wid) base += s_wtot[w];

  const uint32_t Ttop = HW - KSEL;  // 3686
#pragma unroll
  for (int j = 0; j < 16; ++j) {
    uint32_t pin = base + pref[j];
    uint32_t pex = base + (j ? pref[j - 1] : 0u);
    if (pex <= Ttop && Ttop < pin) {          // top crossing (from high end)
      s_bT = (uint32_t)(tid * 16 + j);
      s_kT = pin - Ttop;                       // = KSEL - (elements strictly above)
      s_cT = pin - pex;
    }
    if (pex < KSEL && KSEL <= pin) {          // bottom crossing (from low end)
      s_bB = (uint32_t)(tid * 16 + j);
      s_kB = KSEL - pex;
      s_cB = pin - pex;
    }
  }
  __syncthreads();

  // ---- level 1: build both 10-bit refinements (few survivors -> cheap atomics) ----
  const uint32_t bT = s_bT, bB = s_bB;
#pragma unroll
  for (int i = 0; i < VPT; ++i) {
    uint32_t u = key[i];
    if ((u >> 20) == bT) atomicAdd(&ht[(u >> 10) & 1023u], 1u);
    if ((u >> 20) == bB) atomicAdd(&hb[(u >> 10) & 1023u], 1u);
  }
  __syncthreads();
  if (wid == 0) wave_select(ht, lane, true,  s_cT, s_kT, &s_bT1, &s_kT, &s_cT);
  if (wid == 1) wave_select(hb, lane, false, s_cB, s_kB, &s_bB1, &s_kB, &s_cB);
  __syncthreads();

  // ---- level 2: last 10 bits ----
  const uint32_t pT22 = (bT << 10) | s_bT1;
  const uint32_t pB22 = (bB << 10) | s_bB1;
#pragma unroll
  for (int i = 0; i < VPT; ++i) {
    uint32_t u = key[i];
    if ((u >> 10) == pT22) atomicAdd(&ht[u & 1023u], 1u);
    if ((u >> 10) == pB22) atomicAdd(&hb[u & 1023u], 1u);
  }
  __syncthreads();
  if (wid == 0) wave_select(ht, lane, true,  s_cT, s_kT, &s_bT2, &s_kT, &s_cT);
  if (wid == 1) wave_select(hb, lane, false, s_cB, s_kB, &s_bB2, &s_kB, &s_cB);
  __syncthreads();

  const uint32_t thrT = (pT22 << 10) | s_bT2;   // key of K-th largest
  const uint32_t thrB = (pB22 << 10) | s_bB2;   // key of K-th smallest
  const uint32_t kremT = s_kT, kremB = s_kB;    // tie copies to take at threshold

  // ---- final sums: strictly-beyond + krem * threshold ----
  float st = 0.f, sb = 0.f;
#pragma unroll
  for (int i = 0; i < VPT; ++i) {
    uint32_t u = key[i];
    float v = u2f(u);
    if (u > thrT) st += v;
    if (u < thrB) sb += v;
  }
#pragma unroll
  for (int off = 32; off >= 1; off >>= 1) {
    st += __shfl_down(st, off, 64);
    sb += __shfl_down(sb, off, 64);
  }
  if (lane == 0) { s_red[wid][0] = st; s_red[wid][1] = sb; }
  __syncthreads();
  if (tid == 0) {
    float t = s_red[0][0] + s_red[1][0] + s_red[2][0] + s_red[3][0]
            + (float)kremT * u2f(thrT);
    float b = s_red[0][1] + s_red[1][1] + s_red[2][1] + s_red[3][1]
            + (float)kremB * u2f(thrB);
    out[blockIdx.x] = (t + ALPHA_C * b) * (1.0f / (float)KSEL);
  }
}

extern "C" void kernel_launch(void* const* d_in, const int* in_sizes, int n_in,
                              void* d_out, int out_size, void* d_ws, size_t ws_size,
                              hipStream_t stream) {
  const float* x = (const float*)d_in[0];
  float* out = (float*)d_out;
  wildcat_pool<<<out_size, NT, 0, stream>>>(x, out);  // out_size = 32*512 rows
}